// Round 1
// baseline (636.841 us; speedup 1.0000x reference)
//
#include <hip/hip_runtime.h>

typedef __attribute__((ext_vector_type(8))) short bf16x8;
typedef __attribute__((ext_vector_type(8))) unsigned short u16x8;
typedef __attribute__((ext_vector_type(4))) float f32x4;

#define DEV __device__ __forceinline__

DEV unsigned short f2bf(float f) {
  unsigned u = __float_as_uint(f);
  u = (u + 0x7FFFu + ((u >> 16) & 1u)) >> 16;
  return (unsigned short)u;
}
DEV float bf2f(unsigned short h) { return __uint_as_float(((unsigned)h) << 16); }

// ---------------------------------------------------------------- mask canon
// key_mask representation is ambiguous (bool). Detect deterministically:
//  - any word >1 and != 0x3F800000  -> byte-packed bools
//  - any word == 0x3F800000          -> f32 0/1
//  - else                            -> int32 0/1
__global__ __launch_bounds__(256) void k_mask(const unsigned* __restrict__ raw,
                                              int* __restrict__ canon) {
  __shared__ int s_gt1, s_f32;
  int t = threadIdx.x;
  if (t == 0) { s_gt1 = 0; s_f32 = 0; }
  __syncthreads();
  int gt1 = 0, fv = 0;
  for (int i = t; i < 512; i += 256) {   // only 2048 bytes -> safe for all modes
    unsigned v = raw[i];
    if (v == 0x3F800000u) fv = 1;
    else if (v > 1u) gt1 = 1;
  }
  if (gt1) s_gt1 = 1;
  if (fv)  s_f32 = 1;
  __syncthreads();
  int mode = s_gt1 ? 1 : (s_f32 ? 2 : 0);
  for (int i = t; i < 2048; i += 256) {
    int v;
    if (mode == 1)      v = ((const unsigned char*)raw)[i] ? 1 : 0;
    else if (mode == 2) v = (((const float*)raw)[i] != 0.f) ? 1 : 0;
    else                v = raw[i] ? 1 : 0;
    canon[i] = v;
  }
}

// ---------------------------------------------------------------- layernorm
__global__ __launch_bounds__(64) void k_ln(const float* __restrict__ s,
                                           const float* __restrict__ gamma,
                                           const float* __restrict__ beta,
                                           unsigned short* __restrict__ sn) {
  int row = blockIdx.x, l = threadIdx.x;
  const float* sr = s + (size_t)row * 512 + l * 8;
  float4 x0 = *(const float4*)sr, x1 = *(const float4*)(sr + 4);
  float sum = x0.x + x0.y + x0.z + x0.w + x1.x + x1.y + x1.z + x1.w;
  float sq  = x0.x*x0.x + x0.y*x0.y + x0.z*x0.z + x0.w*x0.w
            + x1.x*x1.x + x1.y*x1.y + x1.z*x1.z + x1.w*x1.w;
#pragma unroll
  for (int off = 32; off >= 1; off >>= 1) {
    sum += __shfl_xor(sum, off);
    sq  += __shfl_xor(sq, off);
  }
  float mu = sum * (1.f / 512.f);
  float rstd = rsqrtf(sq * (1.f / 512.f) - mu * mu + 1e-5f);
  float4 g0 = *(const float4*)(gamma + l * 8), g1 = *(const float4*)(gamma + l * 8 + 4);
  float4 b0 = *(const float4*)(beta + l * 8),  b1 = *(const float4*)(beta + l * 8 + 4);
  u16x8 o;
  o[0] = f2bf((x0.x - mu) * rstd * g0.x + b0.x);
  o[1] = f2bf((x0.y - mu) * rstd * g0.y + b0.y);
  o[2] = f2bf((x0.z - mu) * rstd * g0.z + b0.z);
  o[3] = f2bf((x0.w - mu) * rstd * g0.w + b0.w);
  o[4] = f2bf((x1.x - mu) * rstd * g1.x + b1.x);
  o[5] = f2bf((x1.y - mu) * rstd * g1.y + b1.y);
  o[6] = f2bf((x1.z - mu) * rstd * g1.z + b1.z);
  o[7] = f2bf((x1.w - mu) * rstd * g1.w + b1.w);
  *(u16x8*)(sn + (size_t)row * 512 + l * 8) = o;
}

// ---------------------------------------------------------------- GEMM (2048x512x512)
// A bf16 [2048][512], W f32 [512][512] (row-major, converted to bf16 on stage).
// mode 0: -> q_bf16 [b][h][n][d]   1: -> k_bf16 [b][h][n][d]
// mode 2: -> v_bf16 [b][h][d][n]   3: -> gate f32 = sigmoid(.)
// mode 4: -> d_out f32 = gate * (A@W + b)
__global__ __launch_bounds__(256) void k_gemm(const unsigned short* __restrict__ A,
                                              const float* __restrict__ W,
                                              const float* __restrict__ bvec,
                                              void* __restrict__ outp,
                                              const float* __restrict__ gate,
                                              int mode) {
  int ct = blockIdx.x, rt = blockIdx.y;
  int t = threadIdx.x, l = t & 63, w = t >> 6;
  __shared__ unsigned short As[128 * 40];  // [row][k] pad 40 (16B-aligned rows, spread banks)
  __shared__ unsigned short Bs[128 * 40];  // [col][k]
  f32x4 acc[4][4];
#pragma unroll
  for (int mt = 0; mt < 4; ++mt)
#pragma unroll
    for (int nt = 0; nt < 4; ++nt) acc[mt][nt] = (f32x4){0.f, 0.f, 0.f, 0.f};

  int arow = t >> 1, akc = (t & 1) * 16;
  int bkk = t >> 3, bc0 = (t & 7) * 16;
  int wr = w >> 1, wc = w & 1;

  for (int k0 = 0; k0 < 512; k0 += 32) {
    const u16x8* ap = (const u16x8*)(A + (size_t)(rt * 128 + arow) * 512 + k0 + akc);
    u16x8 a0 = ap[0], a1 = ap[1];
    *(u16x8*)(&As[arow * 40 + akc]) = a0;
    *(u16x8*)(&As[arow * 40 + akc + 8]) = a1;
    const float* wp = W + (size_t)(k0 + bkk) * 512 + ct * 128 + bc0;
#pragma unroll
    for (int i = 0; i < 4; ++i) {
      float4 f = *(const float4*)(wp + i * 4);
      Bs[(bc0 + i * 4 + 0) * 40 + bkk] = f2bf(f.x);
      Bs[(bc0 + i * 4 + 1) * 40 + bkk] = f2bf(f.y);
      Bs[(bc0 + i * 4 + 2) * 40 + bkk] = f2bf(f.z);
      Bs[(bc0 + i * 4 + 3) * 40 + bkk] = f2bf(f.w);
    }
    __syncthreads();
    bf16x8 af[4], bf[4];
#pragma unroll
    for (int mt = 0; mt < 4; ++mt)
      af[mt] = *(const bf16x8*)(&As[(wr * 64 + mt * 16 + (l & 15)) * 40 + (l >> 4) * 8]);
#pragma unroll
    for (int nt = 0; nt < 4; ++nt)
      bf[nt] = *(const bf16x8*)(&Bs[(wc * 64 + nt * 16 + (l & 15)) * 40 + (l >> 4) * 8]);
#pragma unroll
    for (int mt = 0; mt < 4; ++mt)
#pragma unroll
      for (int nt = 0; nt < 4; ++nt)
        acc[mt][nt] = __builtin_amdgcn_mfma_f32_16x16x32_bf16(af[mt], bf[nt], acc[mt][nt], 0, 0, 0);
    __syncthreads();
  }

#pragma unroll
  for (int mt = 0; mt < 4; ++mt)
#pragma unroll
    for (int nt = 0; nt < 4; ++nt) {
      int col = ct * 128 + wc * 64 + nt * 16 + (l & 15);
      float bv = bvec[col];
#pragma unroll
      for (int i = 0; i < 4; ++i) {
        int row = rt * 128 + wr * 64 + mt * 16 + (l >> 4) * 4 + i;
        float val = acc[mt][nt][i] + bv;
        int bb_ = row >> 10, n = row & 1023, hh = col >> 5, d = col & 31;
        if (mode <= 1) {
          ((unsigned short*)outp)[(((size_t)bb_ * 16 + hh) * 1024 + n) * 32 + d] = f2bf(val);
        } else if (mode == 2) {
          ((unsigned short*)outp)[(((size_t)bb_ * 16 + hh) * 32 + d) * 1024 + n] = f2bf(val);
        } else if (mode == 3) {
          ((float*)outp)[(size_t)row * 512 + col] = 1.f / (1.f + __expf(-val));
        } else {
          ((float*)outp)[(size_t)row * 512 + col] = gate[(size_t)row * 512 + col] * val;
        }
      }
    }
}

// ---------------------------------------------------------------- pair bias GEMM
// bias[b][h][n][m] (bf16) = z[b][n][m][:] . Wb[:,h] + bb[h].  One block per (b,n).
__global__ __launch_bounds__(256) void k_bias(const float* __restrict__ z,
                                              const float* __restrict__ Wb,
                                              const float* __restrict__ bbp,
                                              unsigned short* __restrict__ biasb) {
  int bid = blockIdx.x;  // b*1024 + n
  int b = bid >> 10, n = bid & 1023;
  int t = threadIdx.x, l = t & 63, w = t >> 6;
  int hh = l & 15, g = l >> 4;

  bf16x8 wf[4];
#pragma unroll
  for (int ks = 0; ks < 4; ++ks)
#pragma unroll
    for (int j = 0; j < 8; ++j) {
      int c = ks * 32 + g * 8 + j;
      wf[ks][j] = (short)f2bf(Wb[c * 16 + hh]);
    }
  float bbh = bbp[hh];

  for (int mt = 0; mt < 16; ++mt) {
    int m0 = w * 256 + mt * 16;
    const float* zr = z + ((size_t)bid * 1024 + m0 + (l & 15)) * 128;
    f32x4 acc = (f32x4){0.f, 0.f, 0.f, 0.f};
#pragma unroll
    for (int ks = 0; ks < 4; ++ks) {
      const float* zp = zr + ks * 32 + g * 8;
      float4 z0 = *(const float4*)zp, z1 = *(const float4*)(zp + 4);
      bf16x8 af;
      af[0] = (short)f2bf(z0.x); af[1] = (short)f2bf(z0.y);
      af[2] = (short)f2bf(z0.z); af[3] = (short)f2bf(z0.w);
      af[4] = (short)f2bf(z1.x); af[5] = (short)f2bf(z1.y);
      af[6] = (short)f2bf(z1.z); af[7] = (short)f2bf(z1.w);
      acc = __builtin_amdgcn_mfma_f32_16x16x32_bf16(af, wf[ks], acc, 0, 0, 0);
    }
    int m = m0 + g * 4;
    ushort4 o4 = make_ushort4(f2bf(acc[0] + bbh), f2bf(acc[1] + bbh),
                              f2bf(acc[2] + bbh), f2bf(acc[3] + bbh));
    *(ushort4*)(biasb + ((size_t)(b * 16 + hh) * 1024 + n) * 1024 + m) = o4;
  }
}

// ---------------------------------------------------------------- attention
// One block per (b, h, 8-query tile). Full 1024-key softmax in LDS.
__global__ __launch_bounds__(256) void k_attn(const unsigned short* __restrict__ qb,
                                              const unsigned short* __restrict__ kb,
                                              const unsigned short* __restrict__ vb,
                                              const unsigned short* __restrict__ biasb,
                                              const int* __restrict__ maskc,
                                              unsigned short* __restrict__ attn_out) {
  int bid = blockIdx.x;
  int qt = bid & 127, bh = bid >> 7, hh = bh & 15, b = bh >> 4;
  int q0 = qt * 8;
  int t = threadIdx.x, l = t & 63, w = t >> 6;

  __shared__ float sc[8 * 1024];          // idx = q*1024 + (m ^ q)           (bank swizzle)
  __shared__ unsigned short pp[8 * 1024]; // idx = q*1024 + (m ^ (q<<3))      (16B-chunk swizzle)
  __shared__ float ssum[8];
  __shared__ float opart[4][8 * 16];

  int qlocal = l & 15;
  int qcol = (qlocal < 8) ? (q0 + qlocal) : q0;
  bf16x8 qf = *(const bf16x8*)(qb + ((size_t)bh * 1024 + qcol) * 32 + (l >> 4) * 8);
  const float RS = 0.17677669529663687f;  // 1/sqrt(32)

  // P1: QK^T
#pragma unroll 4
  for (int j = 0; j < 16; ++j) {
    int m0 = (w * 16 + j) * 16;
    bf16x8 kf = *(const bf16x8*)(kb + ((size_t)bh * 1024 + m0 + (l & 15)) * 32 + (l >> 4) * 8);
    f32x4 c = (f32x4){0.f, 0.f, 0.f, 0.f};
    c = __builtin_amdgcn_mfma_f32_16x16x32_bf16(kf, qf, c, 0, 0, 0);
    if (qlocal < 8) {
#pragma unroll
      for (int i = 0; i < 4; ++i) {
        int m = m0 + (l >> 4) * 4 + i;
        sc[qlocal * 1024 + (m ^ qlocal)] = c[i] * RS;
      }
    }
  }
  __syncthreads();

  // P2: + bias, mask
  {
    int q2 = t >> 5, lm = t & 31;
    const unsigned short* brow = biasb + ((size_t)bh * 1024 + q0 + q2) * 1024;
    const int* mrow = maskc + b * 1024;
#pragma unroll 4
    for (int j = 0; j < 32; ++j) {
      int m = lm + j * 32;
      int idx = q2 * 1024 + (m ^ q2);
      float bv = bf2f(brow[m]);
      sc[idx] = mrow[m] ? -1e30f : (sc[idx] + bv);
    }
  }
  __syncthreads();

  // P3: softmax (per q row over 1024 keys)
#pragma unroll
  for (int qi = 0; qi < 2; ++qi) {
    int q = w * 2 + qi;
    float vals[16];
    float mx = -3.4e38f;
#pragma unroll
    for (int j = 0; j < 16; ++j) {
      vals[j] = sc[q * 1024 + ((l + j * 64) ^ q)];
      mx = fmaxf(mx, vals[j]);
    }
#pragma unroll
    for (int off = 32; off >= 1; off >>= 1) mx = fmaxf(mx, __shfl_xor(mx, off));
    float sum = 0.f;
#pragma unroll
    for (int j = 0; j < 16; ++j) {
      float e = __expf(vals[j] - mx);
      sum += e;
      pp[q * 1024 + ((l + j * 64) ^ (q << 3))] = f2bf(e);
    }
#pragma unroll
    for (int off = 32; off >= 1; off >>= 1) sum += __shfl_xor(sum, off);
    if (l == 0) ssum[q] = sum;
  }
  __syncthreads();

  // P4: PV
  {
    int dt = w & 1, kh = w >> 1;
    int qc = (qlocal < 8) ? qlocal : 0;
    int d = dt * 16 + (l & 15);
    f32x4 acc = (f32x4){0.f, 0.f, 0.f, 0.f};
    for (int ks = 0; ks < 16; ++ks) {
      int m0 = (kh * 16 + ks) * 32 + (l >> 4) * 8;
      bf16x8 pf = *(const bf16x8*)(&pp[qc * 1024 + (m0 ^ (qc << 3))]);
      bf16x8 vf = *(const bf16x8*)(vb + ((size_t)bh * 32 + d) * 1024 + m0);
      acc = __builtin_amdgcn_mfma_f32_16x16x32_bf16(pf, vf, acc, 0, 0, 0);
    }
#pragma unroll
    for (int i = 0; i < 4; ++i) {
      int q = (l >> 4) * 4 + i;
      if (q < 8) opart[w][q * 16 + (l & 15)] = acc[i];
    }
  }
  __syncthreads();

  // P5: combine halves, normalize, store
  {
    int d2 = t >> 7, q = (t >> 4) & 7, dcol = t & 15;
    float o = opart[d2][q * 16 + dcol] + opart[2 + d2][q * 16 + dcol];
    float s = ssum[q];
    float inv = (s > 0.f) ? 1.f / s : 0.f;
    attn_out[((size_t)b * 1024 + q0 + q) * 512 + hh * 32 + d2 * 16 + dcol] = f2bf(o * inv);
  }
}

// ----------------------------------------------------------------
extern "C" void kernel_launch(void* const* d_in, const int* in_sizes, int n_in,
                              void* d_out, int out_size, void* d_ws, size_t ws_size,
                              hipStream_t stream) {
  (void)in_sizes; (void)n_in; (void)out_size; (void)ws_size;
  const float* s     = (const float*)d_in[0];
  const float* z     = (const float*)d_in[1];
  const unsigned* km = (const unsigned*)d_in[2];
  const float* Wq = (const float*)d_in[3];
  const float* bq = (const float*)d_in[4];
  const float* Wk = (const float*)d_in[5];
  const float* bk = (const float*)d_in[6];
  const float* Wv = (const float*)d_in[7];
  const float* bv = (const float*)d_in[8];
  const float* Wb = (const float*)d_in[9];
  const float* bb = (const float*)d_in[10];
  const float* Wg = (const float*)d_in[11];
  const float* bg = (const float*)d_in[12];
  const float* Wo = (const float*)d_in[13];
  const float* bo = (const float*)d_in[14];
  const float* gamma = (const float*)d_in[15];
  const float* beta  = (const float*)d_in[16];

  char* ws = (char*)d_ws;
  unsigned short* sn    = (unsigned short*)(ws);
  unsigned short* qbuf  = (unsigned short*)(ws + (2ull << 20));
  unsigned short* kbuf  = (unsigned short*)(ws + (4ull << 20));
  unsigned short* vbuf  = (unsigned short*)(ws + (6ull << 20));
  float*          gate  = (float*)(ws + (8ull << 20));
  unsigned short* aout  = (unsigned short*)(ws + (12ull << 20));
  unsigned short* biasb = (unsigned short*)(ws + (14ull << 20));
  int*            maskc = (int*)(ws + (78ull << 20));

  hipLaunchKernelGGL(k_mask, dim3(1), dim3(256), 0, stream, km, maskc);
  hipLaunchKernelGGL(k_ln, dim3(2048), dim3(64), 0, stream, s, gamma, beta, sn);
  dim3 g2(4, 16);
  hipLaunchKernelGGL(k_gemm, g2, dim3(256), 0, stream, sn, Wq, bq, (void*)qbuf, (const float*)nullptr, 0);
  hipLaunchKernelGGL(k_gemm, g2, dim3(256), 0, stream, sn, Wk, bk, (void*)kbuf, (const float*)nullptr, 1);
  hipLaunchKernelGGL(k_gemm, g2, dim3(256), 0, stream, sn, Wv, bv, (void*)vbuf, (const float*)nullptr, 2);
  hipLaunchKernelGGL(k_gemm, g2, dim3(256), 0, stream, sn, Wg, bg, (void*)gate, (const float*)nullptr, 3);
  hipLaunchKernelGGL(k_bias, dim3(2048), dim3(256), 0, stream, z, Wb, bb, biasb);
  hipLaunchKernelGGL(k_attn, dim3(4096), dim3(256), 0, stream, qbuf, kbuf, vbuf, biasb, maskc, aout);
  hipLaunchKernelGGL(k_gemm, g2, dim3(256), 0, stream, aout, Wo, bo, d_out, gate, 4);
}